// Round 1
// baseline (7059.464 us; speedup 1.0000x reference)
//
#include <hip/hip_runtime.h>
#include <math.h>

#define T_STEPS 1024
#define BATCH   512
#define DZ      256
#define DH      256
#define RANK    8
#define DY      16

// Block: 1024 threads = 16 waves, handles 2 batch elements for all T steps.
// Thread (i = tid&255, q = tid>>8): owns output-neuron i, k-quadrant q.
// Register-resident weights: W_zz[i, 64q:64q+64], Wz_in[i, 16q:16q+16], W_in[i, 8q:8q+8].

__global__ __launch_bounds__(1024) void nmrnn_kernel(
    const float* __restrict__ s, const float* __restrict__ c,
    const float* __restrict__ W_zz, const float* __restrict__ Wz_in,
    const float* __restrict__ bz_in, const float* __restrict__ Wz_out,
    const float* __restrict__ bz_out, const float* __restrict__ U,
    const float* __restrict__ V, const float* __restrict__ W_in,
    const float* __restrict__ b_in, const float* __restrict__ W_out,
    const float* __restrict__ b_out,
    float* __restrict__ out, float* __restrict__ states)
{
    __shared__ float tz[2][DZ];        // tanh(z_{t-1}) then tanh(z_t)
    __shared__ float th[2][DH];        // tanh(h_{t-1}) then tanh(h_t)
    __shared__ float zl[2][DZ];        // z_t (for signal dot)
    __shared__ float red[4][2][256];   // cross-quadrant reduction scratch
    __shared__ float scl[2][64];       // [s_t | c_t] per batch element
    __shared__ float wzo[RANK][DZ];    // Wz_out (native layout [r][k])
    __shared__ float vt[RANK][DH];     // V transposed  -> vt[r][k]
    __shared__ float ut[RANK][DH];     // U transposed  -> ut[r][i]
    __shared__ float wo[DY][DH];       // W_out (native layout [y][k])
    __shared__ float gl[2][RANK];      // signal * (tanh(h) @ V)
    __shared__ float bzo[RANK];
    __shared__ float bo[DY];

    const int tid = threadIdx.x;
    const int i   = tid & 255;
    const int q   = tid >> 8;          // 0..3
    const int b0  = blockIdx.x * 2;

    // ---- load register-resident weights ----
    float wzz[64];
    #pragma unroll
    for (int m = 0; m < 64; m += 4) {
        const float4 v4 = *reinterpret_cast<const float4*>(&W_zz[i * 256 + q * 64 + m]);
        wzz[m] = v4.x; wzz[m + 1] = v4.y; wzz[m + 2] = v4.z; wzz[m + 3] = v4.w;
    }
    float wzi[16];
    #pragma unroll
    for (int m = 0; m < 16; m += 4) {
        const float4 v4 = *reinterpret_cast<const float4*>(&Wz_in[i * 64 + q * 16 + m]);
        wzi[m] = v4.x; wzi[m + 1] = v4.y; wzi[m + 2] = v4.z; wzi[m + 3] = v4.w;
    }
    float wi[8];
    #pragma unroll
    for (int m = 0; m < 8; m += 4) {
        const float4 v4 = *reinterpret_cast<const float4*>(&W_in[i * 32 + q * 8 + m]);
        wi[m] = v4.x; wi[m + 1] = v4.y; wi[m + 2] = v4.z; wi[m + 3] = v4.w;
    }

    // ---- stage small matrices in LDS ----
    if (tid < 512) {  // Wz_out: 8*256 = 2048 floats
        const float4 v4 = *reinterpret_cast<const float4*>(&Wz_out[tid * 4]);
        *reinterpret_cast<float4*>(&((float*)wzo)[tid * 4]) = v4;
    }
    {   // W_out: 16*256 = 4096 floats
        const float4 v4 = *reinterpret_cast<const float4*>(&W_out[tid * 4]);
        *reinterpret_cast<float4*>(&((float*)wo)[tid * 4]) = v4;
    }
    if (tid < 256) {  // transpose V, U
        #pragma unroll
        for (int r = 0; r < RANK; ++r) vt[r][tid] = V[tid * RANK + r];
        #pragma unroll
        for (int r = 0; r < RANK; ++r) ut[r][tid] = U[tid * RANK + r];
    }
    if (tid < RANK) bzo[tid] = bz_out[tid];
    if (tid < DY)   bo[tid]  = b_out[tid];

    const float bzi_r = (tid < 512) ? bz_in[i] : 0.f;
    const float bi_r  = (tid < 512) ? b_in[i]  : 0.f;
    float z_r = 0.f, h_r = 0.f;

    if (tid < 512) {  // init state (z0 = h0 = 0)
        tz[q][i] = 0.f; th[q][i] = 0.f; zl[q][i] = 0.f;
    }
    __syncthreads();

    for (int t = 0; t < T_STEPS; ++t) {
        // ---- phase 1: load s_t, c_t into LDS ----
        if (tid < 128) {
            const int b = tid >> 6, r = tid & 63;
            float v;
            if (r < 32) v = s[((size_t)t * BATCH + b0 + b) * 32 + r];
            else        v = c[((size_t)t * BATCH + b0 + b) * 32 + (r - 32)];
            scl[b][r] = v;
        }
        __syncthreads();  // A

        // ---- phase 3: z partial dots (W_zz over quadrant + Wz_in) ----
        {
            float a0 = 0.f, a1 = 0.f;
            #pragma unroll
            for (int m = 0; m < 16; ++m) {
                const float4 t0 = *reinterpret_cast<const float4*>(&tz[0][(q << 6) + (m << 2)]);
                const float4 t1 = *reinterpret_cast<const float4*>(&tz[1][(q << 6) + (m << 2)]);
                a0 = fmaf(wzz[4 * m + 0], t0.x, a0);
                a0 = fmaf(wzz[4 * m + 1], t0.y, a0);
                a0 = fmaf(wzz[4 * m + 2], t0.z, a0);
                a0 = fmaf(wzz[4 * m + 3], t0.w, a0);
                a1 = fmaf(wzz[4 * m + 0], t1.x, a1);
                a1 = fmaf(wzz[4 * m + 1], t1.y, a1);
                a1 = fmaf(wzz[4 * m + 2], t1.z, a1);
                a1 = fmaf(wzz[4 * m + 3], t1.w, a1);
            }
            #pragma unroll
            for (int m = 0; m < 4; ++m) {
                const float4 s0 = *reinterpret_cast<const float4*>(&scl[0][(q << 4) + (m << 2)]);
                const float4 s1 = *reinterpret_cast<const float4*>(&scl[1][(q << 4) + (m << 2)]);
                a0 = fmaf(wzi[4 * m + 0], s0.x, a0);
                a0 = fmaf(wzi[4 * m + 1], s0.y, a0);
                a0 = fmaf(wzi[4 * m + 2], s0.z, a0);
                a0 = fmaf(wzi[4 * m + 3], s0.w, a0);
                a1 = fmaf(wzi[4 * m + 0], s1.x, a1);
                a1 = fmaf(wzi[4 * m + 1], s1.y, a1);
                a1 = fmaf(wzi[4 * m + 2], s1.z, a1);
                a1 = fmaf(wzi[4 * m + 3], s1.w, a1);
            }
            red[q][0][i] = a0;
            red[q][1][i] = a1;
        }
        __syncthreads();  // B

        // ---- phase 5: z update (threads tid<512: b=q) ----
        if (tid < 512) {
            const int b = q;
            const float tmp = red[0][b][i] + red[1][b][i] + red[2][b][i] + red[3][b][i] + bzi_r;
            z_r = 0.99f * z_r + 0.01f * tmp;
            zl[b][i] = z_r;
            tz[b][i] = tanhf(z_r);
            states[((size_t)t * BATCH + b0 + b) * 512 + i] = z_r;
        }
        __syncthreads();  // C

        // ---- phase 7: signal & (tanh(h)@V) group reductions -> gl[b][r] ----
        {
            const int g = tid >> 6, l = tid & 63;
            const int b = g >> 3, r = g & 7;
            float zp = 0.f, hp = 0.f;
            #pragma unroll
            for (int m = 0; m < 4; ++m) {
                const int k = l + 64 * m;
                zp = fmaf(zl[b][k], wzo[r][k], zp);
                hp = fmaf(th[b][k], vt[r][k], hp);
            }
            #pragma unroll
            for (int off = 32; off >= 1; off >>= 1) {
                zp += __shfl_xor(zp, off);
                hp += __shfl_xor(hp, off);
            }
            if (l == 0) {
                const float sig = 1.f / (1.f + __expf(-(zp + bzo[r])));
                gl[b][r] = sig * hp;
            }
        }
        __syncthreads();  // D

        // ---- phase 9: h partial dots (U@g on q==0, W_in slice on all q) ----
        {
            float p0 = 0.f, p1 = 0.f;
            if (q == 0) {
                #pragma unroll
                for (int r = 0; r < RANK; ++r) {
                    const float u = ut[r][i];
                    p0 = fmaf(u, gl[0][r], p0);
                    p1 = fmaf(u, gl[1][r], p1);
                }
            }
            const float4 s0a = *reinterpret_cast<const float4*>(&scl[0][q * 8]);
            const float4 s0b = *reinterpret_cast<const float4*>(&scl[0][q * 8 + 4]);
            const float4 s1a = *reinterpret_cast<const float4*>(&scl[1][q * 8]);
            const float4 s1b = *reinterpret_cast<const float4*>(&scl[1][q * 8 + 4]);
            p0 = fmaf(wi[0], s0a.x, p0); p0 = fmaf(wi[1], s0a.y, p0);
            p0 = fmaf(wi[2], s0a.z, p0); p0 = fmaf(wi[3], s0a.w, p0);
            p0 = fmaf(wi[4], s0b.x, p0); p0 = fmaf(wi[5], s0b.y, p0);
            p0 = fmaf(wi[6], s0b.z, p0); p0 = fmaf(wi[7], s0b.w, p0);
            p1 = fmaf(wi[0], s1a.x, p1); p1 = fmaf(wi[1], s1a.y, p1);
            p1 = fmaf(wi[2], s1a.z, p1); p1 = fmaf(wi[3], s1a.w, p1);
            p1 = fmaf(wi[4], s1b.x, p1); p1 = fmaf(wi[5], s1b.y, p1);
            p1 = fmaf(wi[6], s1b.z, p1); p1 = fmaf(wi[7], s1b.w, p1);
            red[q][0][i] = p0;
            red[q][1][i] = p1;
        }
        __syncthreads();  // E

        // ---- phase 11: h update ----
        if (tid < 512) {
            const int b = q;
            const float tmp = red[0][b][i] + red[1][b][i] + red[2][b][i] + red[3][b][i] + bi_r;
            h_r = 0.9f * h_r + 0.1f * tmp;
            th[b][i] = tanhf(h_r);
            states[((size_t)t * BATCH + b0 + b) * 512 + 256 + i] = h_r;
        }
        __syncthreads();  // F

        // ---- phase 13: outputs (16 groups of 64 lanes, y = group) ----
        {
            const int g = tid >> 6, l = tid & 63;
            float o0 = 0.f, o1 = 0.f;
            #pragma unroll
            for (int m = 0; m < 4; ++m) {
                const int k = l + 64 * m;
                const float w = wo[g][k];
                o0 = fmaf(th[0][k], w, o0);
                o1 = fmaf(th[1][k], w, o1);
            }
            #pragma unroll
            for (int off = 32; off >= 1; off >>= 1) {
                o0 += __shfl_xor(o0, off);
                o1 += __shfl_xor(o1, off);
            }
            if (l == 0) {
                out[((size_t)t * BATCH + b0) * 16 + g]     = o0 + bo[g];
                out[((size_t)t * BATCH + b0 + 1) * 16 + g] = o1 + bo[g];
            }
        }
        // no barrier needed: phase-13 reads (th, wo) are disjoint from next
        // phase-1 writes (scl); barrier A orders everything else.
    }
}

extern "C" void kernel_launch(void* const* d_in, const int* in_sizes, int n_in,
                              void* d_out, int out_size, void* d_ws, size_t ws_size,
                              hipStream_t stream) {
    const float* s     = (const float*)d_in[0];
    const float* c     = (const float*)d_in[1];
    const float* W_zz  = (const float*)d_in[2];
    const float* Wz_in = (const float*)d_in[3];
    const float* bz_in = (const float*)d_in[4];
    const float* Wz_out= (const float*)d_in[5];
    const float* bz_out= (const float*)d_in[6];
    const float* U     = (const float*)d_in[7];
    const float* V     = (const float*)d_in[8];
    const float* W_in  = (const float*)d_in[9];
    const float* b_in  = (const float*)d_in[10];
    const float* W_out = (const float*)d_in[11];
    const float* b_out = (const float*)d_in[12];

    float* out    = (float*)d_out;
    float* states = out + (size_t)T_STEPS * BATCH * DY;

    hipLaunchKernelGGL(nmrnn_kernel, dim3(BATCH / 2), dim3(1024), 0, stream,
                       s, c, W_zz, Wz_in, bz_in, Wz_out, bz_out, U, V,
                       W_in, b_in, W_out, b_out, out, states);
}

// Round 2
// 6086.718 us; speedup vs baseline: 1.1598x; 1.1598x over previous
//
#include <hip/hip_runtime.h>
#include <math.h>

#define T_STEPS 1024
#define BATCH   512
#define DZ      256
#define DH      256
#define RANK    8
#define DY      16

// Block: 1024 threads = 16 waves, handles 2 batch elements for all T steps.
// Thread (i = tid&255, q = tid>>8): owns output-neuron i, k-quadrant q.
// Register-resident weights: W_zz[i, 64q:64q+64], Wz_in[i, 16q:16q+16], W_in[i, 8q:8q+8].
// __launch_bounds__(1024, 4): 4 waves/EU -> 1 block/CU -> VGPR cap 128 (R1 had
// an implicit 64-VGPR cap that spilled the weights to scratch: WRITE_SIZE 3.2GB).

__device__ __forceinline__ float fast_tanh(float x) {
    const float e = __expf(2.0f * x);          // v_exp_f32 path
    return 1.0f - 2.0f / (e + 1.0f);
}

__global__ __launch_bounds__(1024, 4) void nmrnn_kernel(
    const float* __restrict__ s, const float* __restrict__ c,
    const float* __restrict__ W_zz, const float* __restrict__ Wz_in,
    const float* __restrict__ bz_in, const float* __restrict__ Wz_out,
    const float* __restrict__ bz_out, const float* __restrict__ U,
    const float* __restrict__ V, const float* __restrict__ W_in,
    const float* __restrict__ b_in, const float* __restrict__ W_out,
    const float* __restrict__ b_out,
    float* __restrict__ out, float* __restrict__ states)
{
    __shared__ float tz[2][DZ];        // tanh(z_{t-1}) then tanh(z_t)
    __shared__ float th[2][DH];        // tanh(h_{t-1}) then tanh(h_t)
    __shared__ float zl[2][DZ];        // z_t (for signal dot)
    __shared__ float red[4][2][256];   // cross-quadrant reduction scratch
    __shared__ float scl[2][64];       // [s_t | c_t] per batch element
    __shared__ float wzo[RANK][DZ];    // Wz_out (native layout [r][k])
    __shared__ float vt[RANK][DH];     // V transposed  -> vt[r][k]
    __shared__ float ut[RANK][DH];     // U transposed  -> ut[r][i]
    __shared__ float wo[DY][DH];       // W_out (native layout [y][k])
    __shared__ float gl[2][RANK];      // signal * (tanh(h) @ V)
    __shared__ float bzo[RANK];
    __shared__ float bo[DY];

    const int tid = threadIdx.x;
    const int i   = tid & 255;
    const int q   = tid >> 8;          // 0..3
    const int b0  = blockIdx.x * 2;

    // ---- load register-resident weights ----
    float wzz[64];
    #pragma unroll
    for (int m = 0; m < 64; m += 4) {
        const float4 v4 = *reinterpret_cast<const float4*>(&W_zz[i * 256 + q * 64 + m]);
        wzz[m] = v4.x; wzz[m + 1] = v4.y; wzz[m + 2] = v4.z; wzz[m + 3] = v4.w;
    }
    float wzi[16];
    #pragma unroll
    for (int m = 0; m < 16; m += 4) {
        const float4 v4 = *reinterpret_cast<const float4*>(&Wz_in[i * 64 + q * 16 + m]);
        wzi[m] = v4.x; wzi[m + 1] = v4.y; wzi[m + 2] = v4.z; wzi[m + 3] = v4.w;
    }
    float wi[8];
    #pragma unroll
    for (int m = 0; m < 8; m += 4) {
        const float4 v4 = *reinterpret_cast<const float4*>(&W_in[i * 32 + q * 8 + m]);
        wi[m] = v4.x; wi[m + 1] = v4.y; wi[m + 2] = v4.z; wi[m + 3] = v4.w;
    }

    // ---- stage small matrices in LDS ----
    if (tid < 512) {  // Wz_out: 8*256 = 2048 floats
        const float4 v4 = *reinterpret_cast<const float4*>(&Wz_out[tid * 4]);
        *reinterpret_cast<float4*>(&((float*)wzo)[tid * 4]) = v4;
    }
    {   // W_out: 16*256 = 4096 floats
        const float4 v4 = *reinterpret_cast<const float4*>(&W_out[tid * 4]);
        *reinterpret_cast<float4*>(&((float*)wo)[tid * 4]) = v4;
    }
    if (tid < 256) {  // transpose V, U
        #pragma unroll
        for (int r = 0; r < RANK; ++r) vt[r][tid] = V[tid * RANK + r];
        #pragma unroll
        for (int r = 0; r < RANK; ++r) ut[r][tid] = U[tid * RANK + r];
    }
    if (tid < RANK) bzo[tid] = bz_out[tid];
    if (tid < DY)   bo[tid]  = b_out[tid];

    const float bzi_r = (tid < 512) ? bz_in[i] : 0.f;
    const float bi_r  = (tid < 512) ? b_in[i]  : 0.f;
    float z_r = 0.f, h_r = 0.f;

    if (tid < 512) {  // init state (z0 = h0 = 0)
        tz[q][i] = 0.f; th[q][i] = 0.f; zl[q][i] = 0.f;
    }
    __syncthreads();

    for (int t = 0; t < T_STEPS; ++t) {
        // ---- phase 1: load s_t, c_t into LDS ----
        if (tid < 128) {
            const int b = tid >> 6, r = tid & 63;
            float v;
            if (r < 32) v = s[((size_t)t * BATCH + b0 + b) * 32 + r];
            else        v = c[((size_t)t * BATCH + b0 + b) * 32 + (r - 32)];
            scl[b][r] = v;
        }
        __syncthreads();  // A

        // ---- phase 3: z partial dots (W_zz over quadrant + Wz_in) ----
        {
            float a0 = 0.f, a1 = 0.f;
            #pragma unroll
            for (int m = 0; m < 16; ++m) {
                const float4 t0 = *reinterpret_cast<const float4*>(&tz[0][(q << 6) + (m << 2)]);
                const float4 t1 = *reinterpret_cast<const float4*>(&tz[1][(q << 6) + (m << 2)]);
                a0 = fmaf(wzz[4 * m + 0], t0.x, a0);
                a0 = fmaf(wzz[4 * m + 1], t0.y, a0);
                a0 = fmaf(wzz[4 * m + 2], t0.z, a0);
                a0 = fmaf(wzz[4 * m + 3], t0.w, a0);
                a1 = fmaf(wzz[4 * m + 0], t1.x, a1);
                a1 = fmaf(wzz[4 * m + 1], t1.y, a1);
                a1 = fmaf(wzz[4 * m + 2], t1.z, a1);
                a1 = fmaf(wzz[4 * m + 3], t1.w, a1);
            }
            #pragma unroll
            for (int m = 0; m < 4; ++m) {
                const float4 s0 = *reinterpret_cast<const float4*>(&scl[0][(q << 4) + (m << 2)]);
                const float4 s1 = *reinterpret_cast<const float4*>(&scl[1][(q << 4) + (m << 2)]);
                a0 = fmaf(wzi[4 * m + 0], s0.x, a0);
                a0 = fmaf(wzi[4 * m + 1], s0.y, a0);
                a0 = fmaf(wzi[4 * m + 2], s0.z, a0);
                a0 = fmaf(wzi[4 * m + 3], s0.w, a0);
                a1 = fmaf(wzi[4 * m + 0], s1.x, a1);
                a1 = fmaf(wzi[4 * m + 1], s1.y, a1);
                a1 = fmaf(wzi[4 * m + 2], s1.z, a1);
                a1 = fmaf(wzi[4 * m + 3], s1.w, a1);
            }
            red[q][0][i] = a0;
            red[q][1][i] = a1;
        }
        __syncthreads();  // B

        // ---- phase 5: z update (threads tid<512: b=q) ----
        if (tid < 512) {
            const int b = q;
            const float tmp = red[0][b][i] + red[1][b][i] + red[2][b][i] + red[3][b][i] + bzi_r;
            z_r = 0.99f * z_r + 0.01f * tmp;
            zl[b][i] = z_r;
            tz[b][i] = fast_tanh(z_r);
            states[((size_t)t * BATCH + b0 + b) * 512 + i] = z_r;
        }
        __syncthreads();  // C

        // ---- phase 7: signal & (tanh(h)@V) group reductions -> gl[b][r] ----
        {
            const int g = tid >> 6, l = tid & 63;
            const int b = g >> 3, r = g & 7;
            float zp = 0.f, hp = 0.f;
            #pragma unroll
            for (int m = 0; m < 4; ++m) {
                const int k = l + 64 * m;
                zp = fmaf(zl[b][k], wzo[r][k], zp);
                hp = fmaf(th[b][k], vt[r][k], hp);
            }
            #pragma unroll
            for (int off = 32; off >= 1; off >>= 1) {
                zp += __shfl_xor(zp, off);
                hp += __shfl_xor(hp, off);
            }
            if (l == 0) {
                const float sig = 1.f / (1.f + __expf(-(zp + bzo[r])));
                gl[b][r] = sig * hp;
            }
        }
        __syncthreads();  // D

        // ---- phase 9: h partial dots (U@g on q==0, W_in slice on all q) ----
        {
            float p0 = 0.f, p1 = 0.f;
            if (q == 0) {
                #pragma unroll
                for (int r = 0; r < RANK; ++r) {
                    const float u = ut[r][i];
                    p0 = fmaf(u, gl[0][r], p0);
                    p1 = fmaf(u, gl[1][r], p1);
                }
            }
            const float4 s0a = *reinterpret_cast<const float4*>(&scl[0][q * 8]);
            const float4 s0b = *reinterpret_cast<const float4*>(&scl[0][q * 8 + 4]);
            const float4 s1a = *reinterpret_cast<const float4*>(&scl[1][q * 8]);
            const float4 s1b = *reinterpret_cast<const float4*>(&scl[1][q * 8 + 4]);
            p0 = fmaf(wi[0], s0a.x, p0); p0 = fmaf(wi[1], s0a.y, p0);
            p0 = fmaf(wi[2], s0a.z, p0); p0 = fmaf(wi[3], s0a.w, p0);
            p0 = fmaf(wi[4], s0b.x, p0); p0 = fmaf(wi[5], s0b.y, p0);
            p0 = fmaf(wi[6], s0b.z, p0); p0 = fmaf(wi[7], s0b.w, p0);
            p1 = fmaf(wi[0], s1a.x, p1); p1 = fmaf(wi[1], s1a.y, p1);
            p1 = fmaf(wi[2], s1a.z, p1); p1 = fmaf(wi[3], s1a.w, p1);
            p1 = fmaf(wi[4], s1b.x, p1); p1 = fmaf(wi[5], s1b.y, p1);
            p1 = fmaf(wi[6], s1b.z, p1); p1 = fmaf(wi[7], s1b.w, p1);
            red[q][0][i] = p0;
            red[q][1][i] = p1;
        }
        __syncthreads();  // E

        // ---- phase 11: h update ----
        if (tid < 512) {
            const int b = q;
            const float tmp = red[0][b][i] + red[1][b][i] + red[2][b][i] + red[3][b][i] + bi_r;
            h_r = 0.9f * h_r + 0.1f * tmp;
            th[b][i] = fast_tanh(h_r);
            states[((size_t)t * BATCH + b0 + b) * 512 + 256 + i] = h_r;
        }
        __syncthreads();  // F

        // ---- phase 13: outputs (16 groups of 64 lanes, y = group) ----
        {
            const int g = tid >> 6, l = tid & 63;
            float o0 = 0.f, o1 = 0.f;
            #pragma unroll
            for (int m = 0; m < 4; ++m) {
                const int k = l + 64 * m;
                const float w = wo[g][k];
                o0 = fmaf(th[0][k], w, o0);
                o1 = fmaf(th[1][k], w, o1);
            }
            #pragma unroll
            for (int off = 32; off >= 1; off >>= 1) {
                o0 += __shfl_xor(o0, off);
                o1 += __shfl_xor(o1, off);
            }
            if (l == 0) {
                out[((size_t)t * BATCH + b0) * 16 + g]     = o0 + bo[g];
                out[((size_t)t * BATCH + b0 + 1) * 16 + g] = o1 + bo[g];
            }
        }
        // no barrier needed: phase-13 reads (th, wo) are disjoint from next
        // phase-1 writes (scl); barrier A orders everything else.
    }
}

extern "C" void kernel_launch(void* const* d_in, const int* in_sizes, int n_in,
                              void* d_out, int out_size, void* d_ws, size_t ws_size,
                              hipStream_t stream) {
    const float* s     = (const float*)d_in[0];
    const float* c     = (const float*)d_in[1];
    const float* W_zz  = (const float*)d_in[2];
    const float* Wz_in = (const float*)d_in[3];
    const float* bz_in = (const float*)d_in[4];
    const float* Wz_out= (const float*)d_in[5];
    const float* bz_out= (const float*)d_in[6];
    const float* U     = (const float*)d_in[7];
    const float* V     = (const float*)d_in[8];
    const float* W_in  = (const float*)d_in[9];
    const float* b_in  = (const float*)d_in[10];
    const float* W_out = (const float*)d_in[11];
    const float* b_out = (const float*)d_in[12];

    float* out    = (float*)d_out;
    float* states = out + (size_t)T_STEPS * BATCH * DY;

    hipLaunchKernelGGL(nmrnn_kernel, dim3(BATCH / 2), dim3(1024), 0, stream,
                       s, c, W_zz, Wz_in, bz_in, Wz_out, bz_out, U, V,
                       W_in, b_in, W_out, b_out, out, states);
}